// Round 6
// baseline (18.954 us; speedup 1.0000x reference)
//
#include <hip/hip_runtime.h>
#include <math.h>

// Tropical (min-plus) linear: out[b,o] = min_i(X[b,i] + W[o,i])
// B=1024, I=512, O=512 fp32. Pure-VALU problem (no min-plus MFMA).
//
// Round-6: round-5 structure + PACKED FP32 ADDS.
//  - Inner math on f32x2: c = x2 + w2 -> v_pk_add_f32 (full-rate packed
//    fp32 on CDNA3/4), then acc = v_min3_f32(c.x, c.y, acc).
//    4 inst per (m,n,4k) instead of 6  =>  1.0 VALU inst per candidate
//    (structural floor: min has no packed form).
//  - X block tile (16 b x 512 k = 32 KB) staged in LDS once via
//    global_load_lds; main-loop X reads are broadcast ds_read_b128.
//  - W streams from L1 per-lane coalesced, unique addresses.
//  - lane = (og[2], k16[4]); acc 8b x 4o per thread; 4-step compacting
//    butterfly min over k16 bits; 2 outputs/thread stored.
//  - Grid 1024 blocks (16 b x 32 o), XCD-swizzled, 4 waves/SIMD.

#define B_SZ  1024
#define O_F   512
#define I_F   512
#define MB    8      // b rows per thread (and per wave)
#define NO    4      // o per thread (wave covers 16 o)
#define NTHR  256

typedef __attribute__((ext_vector_type(4))) float f32x4;
typedef __attribute__((ext_vector_type(2))) float f32x2;

__global__ __launch_bounds__(NTHR, 4)
void tropical_v6(const float* __restrict__ X,
                 const float* __restrict__ W,
                 float* __restrict__ out) {
  __shared__ f32x4 Xs[16 * 128];   // 32 KB: [b(16)][k4(128)] linear

  const int tid  = threadIdx.x;
  const int wv   = tid >> 6;
  const int lane = tid & 63;
  const int k16  = lane & 15;   // k4 position within 16-lane group
  const int og   = lane >> 4;   // o subgroup 0..3

  // Block tile: 16 b x 32 o; b varies fastest within an XCD (W-panel L2 reuse).
  const int bid = blockIdx.x;
  const int swz = (bid & 7) * 128 + (bid >> 3);   // bijective, 1024 % 8 == 0
  const int ot  = swz >> 6;                       // 16 o-tiles of 32
  const int bt  = swz & 63;                       // 64 b-tiles of 16
  const int b0b = bt * 16;                        // block b base
  const int o0  = ot * 32 + (wv & 1) * 16;        // wave o base
  const int bw  = (wv >> 1) * 8;                  // wave b offset in tile

  const f32x4* __restrict__ Xv = reinterpret_cast<const f32x4*>(X);
  const f32x4* __restrict__ Wv = reinterpret_cast<const f32x4*>(W);
  const int R4 = I_F / 4;   // 128 float4 per row

  // ---- stage X tile once: 2048 float4 = 8 rounds x 256 lanes ----
#pragma unroll
  for (int it = 0; it < 8; ++it) {
    const int slot0 = (wv * 8 + it) * 64;          // wave-uniform LDS slot
    const int f     = slot0 + lane;                // 0..2047
    const f32x4* src = &Xv[(size_t)(b0b + (f >> 7)) * R4 + (f & 127)];
    __builtin_amdgcn_global_load_lds(
        (const __attribute__((address_space(1))) void*)src,
        (__attribute__((address_space(3))) void*)&Xs[slot0],
        16, 0, 0);
  }
  __syncthreads();   // drains vmcnt; only barrier in the kernel

  float acc[MB][NO];
#pragma unroll
  for (int m = 0; m < MB; ++m)
#pragma unroll
    for (int n = 0; n < NO; ++n) acc[m][n] = __builtin_inff();

#pragma unroll
  for (int c = 0; c < I_F / 64; ++c) {             // 8 chunks of 64 k
    const int k4 = c * 16 + k16;
    f32x2 xlo[MB], xhi[MB];
#pragma unroll
    for (int m = 0; m < MB; ++m) {
      const f32x4 x4 = Xs[(bw + m) * 128 + k4];    // ds_read_b128, broadcast
      xlo[m] = (f32x2){x4.x, x4.y};
      xhi[m] = (f32x2){x4.z, x4.w};
    }
#pragma unroll
    for (int n = 0; n < NO; ++n) {
      const f32x4 w4 = Wv[(size_t)(o0 + n * 4 + og) * R4 + k4];  // L1, unique
      const f32x2 wlo = (f32x2){w4.x, w4.y};
      const f32x2 whi = (f32x2){w4.z, w4.w};
#pragma unroll
      for (int m = 0; m < MB; ++m) {
        const f32x2 clo = xlo[m] + wlo;            // v_pk_add_f32
        const f32x2 chi = xhi[m] + whi;            // v_pk_add_f32
        acc[m][n] = fminf(fminf(clo.x, clo.y), acc[m][n]);   // v_min3_f32
        acc[m][n] = fminf(fminf(chi.x, chi.y), acc[m][n]);   // v_min3_f32
      }
    }
  }

  // ---- compacting butterfly min-reduce over lane bits 0..3 (k16) ----
  float v0[32];
#pragma unroll
  for (int m = 0; m < MB; ++m)
#pragma unroll
    for (int n = 0; n < NO; ++n) v0[(m << 2) | n] = acc[m][n];

  const bool bb0 = (k16 & 1);
  float v1[16];
#pragma unroll
  for (int i = 0; i < 16; ++i) {
    float keep = bb0 ? v0[2 * i + 1] : v0[2 * i];
    float send = bb0 ? v0[2 * i]     : v0[2 * i + 1];
    v1[i] = fminf(keep, __shfl_xor(send, 1, 64));
  }
  const bool bb1 = (k16 >> 1) & 1;
  float v2[8];
#pragma unroll
  for (int i = 0; i < 8; ++i) {
    float keep = bb1 ? v1[2 * i + 1] : v1[2 * i];
    float send = bb1 ? v1[2 * i]     : v1[2 * i + 1];
    v2[i] = fminf(keep, __shfl_xor(send, 2, 64));
  }
  const bool bb2 = (k16 >> 2) & 1;
  float v3[4];
#pragma unroll
  for (int i = 0; i < 4; ++i) {
    float keep = bb2 ? v2[2 * i + 1] : v2[2 * i];
    float send = bb2 ? v2[2 * i]     : v2[2 * i + 1];
    v3[i] = fminf(keep, __shfl_xor(send, 4, 64));
  }
  const bool bb3 = (k16 >> 3) & 1;
  float v4[2];
#pragma unroll
  for (int i = 0; i < 2; ++i) {
    float keep = bb3 ? v3[2 * i + 1] : v3[2 * i];
    float send = bb3 ? v3[2 * i]     : v3[2 * i + 1];
    v4[i] = fminf(keep, __shfl_xor(send, 8, 64));
  }

  // lane holds items j = k16 + 16*h  ->  m = (k16>>2) + 4h, n = k16&3
  const int mrow = k16 >> 2;
  const int ncol = k16 & 3;
#pragma unroll
  for (int h = 0; h < 2; ++h) {
    out[(size_t)(b0b + bw + 4 * h + mrow) * O_F + o0 + 4 * ncol + og] = v4[h];
  }
}

extern "C" void kernel_launch(void* const* d_in, const int* in_sizes, int n_in,
                              void* d_out, int out_size, void* d_ws, size_t ws_size,
                              hipStream_t stream) {
  const float* X = (const float*)d_in[0];
  const float* W = (const float*)d_in[1];
  float* out     = (float*)d_out;

  hipLaunchKernelGGL(tropical_v6, dim3(1024), dim3(NTHR), 0, stream,
                     X, W, out);
}

// Round 7
// 17.802 us; speedup vs baseline: 1.0647x; 1.0647x over previous
//
#include <hip/hip_runtime.h>
#include <math.h>

// Tropical (min-plus) linear: out[b,o] = min_i(X[b,i] + W[o,i])
// B=1024, I=512, O=512 fp32. Pure-VALU problem (no min-plus MFMA).
//
// Round-7: round-5 structure, 2x OCCUPANCY.
//  - Tile halved to 8b x 32o -> grid 2048 blocks = 8 blocks/CU,
//    __launch_bounds__(256, 8) (8 waves/SIMD, VGPR<=64, ~50 live).
//    Same total VALU work; 2x waves to hide W-load (L2) latency.
//  - X block tile (8 b x 512 k = 16 KB) staged in LDS once via
//    global_load_lds; main-loop X reads are broadcast ds_read_b128.
//  - W streams from L1/L2 per-lane coalesced, unique addresses.
//  - lane = (og[2], k16[4]); acc 4b x 4o per thread; 4-step compacting
//    butterfly min over k16 bits -> 1 finished output per thread.

#define B_SZ  1024
#define O_F   512
#define I_F   512
#define MB    4      // b rows per thread (and per wave)
#define NO    4      // o per thread (wave covers 16 o)
#define NTHR  256

typedef __attribute__((ext_vector_type(4))) float f32x4;

__global__ __launch_bounds__(NTHR, 8)
void tropical_v7(const float* __restrict__ X,
                 const float* __restrict__ W,
                 float* __restrict__ out) {
  __shared__ f32x4 Xs[8 * 128];   // 16 KB: [b(8)][k4(128)] linear

  const int tid  = threadIdx.x;
  const int wv   = tid >> 6;
  const int lane = tid & 63;
  const int k16  = lane & 15;   // k4 position within 16-lane group
  const int og   = lane >> 4;   // o subgroup 0..3

  // Block tile: 8 b x 32 o. 2048 tiles: 128 b-tiles x 16 o-tiles.
  // XCD swizzle (bijective, 2048 % 8 == 0): b varies fastest per XCD chunk.
  const int bid = blockIdx.x;
  const int swz = (bid & 7) * 256 + (bid >> 3);
  const int ot  = swz >> 7;                       // 16 o-tiles of 32
  const int bt  = swz & 127;                      // 128 b-tiles of 8
  const int b0b = bt * 8;                         // block b base
  const int o0  = ot * 32 + (wv & 1) * 16;        // wave o base
  const int bw  = (wv >> 1) * MB;                 // wave b offset in tile

  const f32x4* __restrict__ Xv = reinterpret_cast<const f32x4*>(X);
  const f32x4* __restrict__ Wv = reinterpret_cast<const f32x4*>(W);
  const int R4 = I_F / 4;   // 128 float4 per row

  // ---- stage X tile once: 1024 float4 = 4 rounds x 256 lanes ----
#pragma unroll
  for (int it = 0; it < 4; ++it) {
    const int slot0 = (wv * 4 + it) * 64;          // wave-uniform LDS slot
    const int f     = slot0 + lane;                // 0..1023
    const f32x4* src = &Xv[(size_t)(b0b + (f >> 7)) * R4 + (f & 127)];
    __builtin_amdgcn_global_load_lds(
        (const __attribute__((address_space(1))) void*)src,
        (__attribute__((address_space(3))) void*)&Xs[slot0],
        16, 0, 0);
  }
  __syncthreads();   // drains vmcnt; only barrier in the kernel

  float acc[MB][NO];
#pragma unroll
  for (int m = 0; m < MB; ++m)
#pragma unroll
    for (int n = 0; n < NO; ++n) acc[m][n] = __builtin_inff();

#pragma unroll
  for (int c = 0; c < I_F / 64; ++c) {             // 8 chunks of 64 k
    const int k4 = c * 16 + k16;
    f32x4 x4[MB];
#pragma unroll
    for (int m = 0; m < MB; ++m)
      x4[m] = Xs[(bw + m) * 128 + k4];             // ds_read_b128, broadcast
#pragma unroll
    for (int n = 0; n < NO; ++n) {
      const f32x4 w4 = Wv[(size_t)(o0 + n * 4 + og) * R4 + k4];  // L1, unique
#pragma unroll
      for (int m = 0; m < MB; ++m) {
        float c0 = x4[m].x + w4.x;
        float c1 = x4[m].y + w4.y;
        float c2 = x4[m].z + w4.z;
        float c3 = x4[m].w + w4.w;
        acc[m][n] = fminf(fminf(c0, c1), acc[m][n]);   // v_min3_f32
        acc[m][n] = fminf(fminf(c2, c3), acc[m][n]);   // v_min3_f32
      }
    }
  }

  // ---- compacting butterfly min-reduce over lane bits 0..3 (k16) ----
  // items j = (m<<2)|n ; step s fixes j-bit s == lane-bit s.
  float v0[16];
#pragma unroll
  for (int m = 0; m < MB; ++m)
#pragma unroll
    for (int n = 0; n < NO; ++n) v0[(m << 2) | n] = acc[m][n];

  const bool bb0 = (k16 & 1);
  float v1[8];
#pragma unroll
  for (int i = 0; i < 8; ++i) {
    float keep = bb0 ? v0[2 * i + 1] : v0[2 * i];
    float send = bb0 ? v0[2 * i]     : v0[2 * i + 1];
    v1[i] = fminf(keep, __shfl_xor(send, 1, 64));
  }
  const bool bb1 = (k16 >> 1) & 1;
  float v2[4];
#pragma unroll
  for (int i = 0; i < 4; ++i) {
    float keep = bb1 ? v1[2 * i + 1] : v1[2 * i];
    float send = bb1 ? v1[2 * i]     : v1[2 * i + 1];
    v2[i] = fminf(keep, __shfl_xor(send, 2, 64));
  }
  const bool bb2 = (k16 >> 2) & 1;
  float v3[2];
#pragma unroll
  for (int i = 0; i < 2; ++i) {
    float keep = bb2 ? v2[2 * i + 1] : v2[2 * i];
    float send = bb2 ? v2[2 * i]     : v2[2 * i + 1];
    v3[i] = fminf(keep, __shfl_xor(send, 4, 64));
  }
  const bool bb3 = (k16 >> 3) & 1;
  {
    float keep = bb3 ? v3[1] : v3[0];
    float send = bb3 ? v3[0] : v3[1];
    const float r = fminf(keep, __shfl_xor(send, 8, 64));
    // lane holds item j = k16 -> m = k16>>2, n = k16&3
    const int mrow = k16 >> 2;
    const int ncol = k16 & 3;
    out[(size_t)(b0b + bw + mrow) * O_F + o0 + 4 * ncol + og] = r;
  }
}

extern "C" void kernel_launch(void* const* d_in, const int* in_sizes, int n_in,
                              void* d_out, int out_size, void* d_ws, size_t ws_size,
                              hipStream_t stream) {
  const float* X = (const float*)d_in[0];
  const float* W = (const float*)d_in[1];
  float* out     = (float*)d_out;

  hipLaunchKernelGGL(tropical_v7, dim3(2048), dim3(NTHR), 0, stream,
                     X, W, out);
}